// Round 9
// baseline (94.956 us; speedup 1.0000x reference)
//
#include <hip/hip_runtime.h>
#include <math.h>

// Problem dims (fixed by setup_inputs): B=2, D=64, H=96, W=96, fp32.
#define BDIM 2
#define DDIM 64
#define HDIM 96
#define WDIM 96

// Capped-EDT window optimization (validated R5-R8, absmax 0.0): capping
// squared distances at 25 preserves the loss weight BIT-EXACTLY, so the 3D
// EDT is local (+-4 halo per axis) and fully fusable.
//
// R9: row-per-thread register W-pass (no mask LDS, 3 barriers total),
// u16-packed (p,n) per voxel with v_pk_min_u16 taps for the H/D passes.
#define DT 8
#define HT 8
#define WT 32
#define DH 16            // DT + 8
#define HH 16            // HT + 8
#define NROWS (DH * HH)  // 256 (d,h) rows = 1 per thread
#define SWSTR 36         // swpn row stride in words (36%32=4: b128 conflict-free)
#define NBLK  (BDIM * (DDIM / DT) * (HDIM / HT) * (WDIM / WT))  // 576

typedef unsigned short ushort2v __attribute__((ext_vector_type(2)));

// ---------------------------------------------------------------------------
// Kernel 1: zero the accumulators + completion counter (ws is poisoned 0xAA).
// ---------------------------------------------------------------------------
__global__ void init_acc(float* __restrict__ acc) {
    if (threadIdx.x < 4) acc[threadIdx.x] = 0.0f;
    if (threadIdx.x == 4) ((int*)acc)[4] = 0;
}

// per-byte unsigned min of 4 packed uint8 (requires all bytes <= 127).
__device__ __forceinline__ unsigned vminu4(unsigned a, unsigned b) {
    unsigned c = ((a | 0x80808080u) - b) & 0x80808080u;
    unsigned m = (c - (c >> 7)) | c;     // 0x80 -> 0xFF, 0 -> 0
    return a ^ ((a ^ b) & m);            // m=FF -> b, m=0 -> a
}

// per-u16-lane unsigned min of packed (p,n)
__device__ __forceinline__ unsigned pkmin(unsigned a, unsigned b) {
    ushort2v r = __builtin_elementwise_min(__builtin_bit_cast(ushort2v, a),
                                           __builtin_bit_cast(ushort2v, b));
    return __builtin_bit_cast(unsigned, r);
}

// bytes t..t+3 of the 12-byte window {lo,hi} (little-endian byte order)
__device__ __forceinline__ unsigned shiftw(unsigned lo, unsigned hi, int t) {
#if __has_builtin(__builtin_amdgcn_alignbyte)
    return __builtin_amdgcn_alignbyte(hi, lo, t);
#else
    return (lo >> (8 * t)) | (hi << (32 - 8 * t));
#endif
}

// W-pass for one packed quad of 0/1 mask bytes -> capped dist2 (<=25)/byte.
__device__ __forceinline__ unsigned wpass_quad(unsigned W0, unsigned W1, unsigned W2) {
    unsigned m = 0x19191919u - W1 * 25u;                   // d=0
    unsigned u08 = W0 | W2;                                // d=+-4
    m = vminu4(m, 0x19191919u - u08 * 9u);
    unsigned u17 = shiftw(W0, W1, 1) | shiftw(W1, W2, 3);  // d=+-3
    m = vminu4(m, 0x19191919u - u17 * 16u);
    unsigned u26 = shiftw(W0, W1, 2) | shiftw(W1, W2, 2);  // d=+-2
    m = vminu4(m, 0x19191919u - u26 * 21u);
    unsigned u35 = shiftw(W0, W1, 3) | shiftw(W1, W2, 1);  // d=+-1
    m = vminu4(m, 0x19191919u - u35 * 24u);
    return m;
}

// ---------------------------------------------------------------------------
// Kernel 2: fully fused boundary loss. grid = 576 blocks x 256 threads.
// ---------------------------------------------------------------------------
__global__ __launch_bounds__(256) void boundary_fused(const float* __restrict__ pred,
                                                      const float* __restrict__ target,
                                                      float* __restrict__ acc,
                                                      float* __restrict__ out) {
    __shared__ __align__(16) unsigned swpn[NROWS * SWSTR];  // (p|n<<16) per voxel, 36 KB
    __shared__ unsigned whpn[DH * HT * WT];                 // W+H packed, 16 KB
    __shared__ float rsum[8];

    const int tid = threadIdx.x;
    int x = blockIdx.x;
    const int wt = x % 3;  x /= 3;
    const int ht = x % 12; x /= 12;
    const int dt = x % 8;
    const int bi = x / 8;
    const int d0 = dt * DT, h0 = ht * HT, w0 = wt * WT;

    // ---- stage A: row-per-thread mask load + W pass entirely in registers ----
    {
        const int r  = tid;                    // (d,h) row 0..255
        const int dr = r >> 4, hr = r & 15;
        const int d = d0 - 4 + dr, h = h0 - 4 + hr;
        const bool rowvalid = ((unsigned)d < DDIM) && ((unsigned)h < HDIM);
        const unsigned rv = rowvalid ? 0x01010101u : 0u;
        const float* rowp = target + ((size_t)(bi * DDIM + d) * HDIM + h) * WDIM + (w0 - 4);

        unsigned Wf[10], Wb[10];
        #pragma unroll
        for (int q = 0; q < 10; ++q) {
            unsigned vbq = 0x01010101u;
            if (q == 0 && wt == 0) vbq = 0u;   // w -4..-1 outside volume
            if (q == 9 && wt == 2) vbq = 0u;   // w 96..99 outside volume
            unsigned fg = 0u;
            if (rowvalid && vbq) {             // 10 independent float4 loads (MLP)
                const float4 v = *(const float4*)(rowp + 4 * q);
                fg = (unsigned)(v.x > 0.5f)         | ((unsigned)(v.y > 0.5f) << 8) |
                     ((unsigned)(v.z > 0.5f) << 16) | ((unsigned)(v.w > 0.5f) << 24);
            }
            Wf[q] = fg;
            Wb[q] = (fg ^ 0x01010101u) & vbq & rv;
        }
        #pragma unroll
        for (int q = 0; q < 8; ++q) {
            const unsigned nb = wpass_quad(Wf[q], Wf[q + 1], Wf[q + 2]);  // dist2->fg
            const unsigned pb = wpass_quad(Wb[q], Wb[q + 1], Wb[q + 2]);  // dist2->bg
            uint4 e;
            e.x = (pb & 0xFFu)         | ((nb & 0xFFu) << 16);
            e.y = ((pb >> 8) & 0xFFu)  | (((nb >> 8) & 0xFFu) << 16);
            e.z = ((pb >> 16) & 0xFFu) | (((nb >> 16) & 0xFFu) << 16);
            e.w = (pb >> 24)           | ((nb >> 24) << 16);
            *(uint4*)&swpn[r * SWSTR + 4 * q] = e;
        }
    }
    __syncthreads();

    // ---- stage B: H pass, 9-tap packed u16 min-plus ----
    #pragma unroll
    for (int k = 0; k < 16; ++k) {
        const int idx = tid + 256 * k;         // (dr 0..15, hh 0..7, c 0..31)
        const int c   = idx & 31;
        const int hh  = (idx >> 5) & 7;
        const int dr  = idx >> 8;
        unsigned a = 0x00190019u;              // (25,25) cap
        #pragma unroll
        for (int t = 0; t < 9; ++t) {
            const unsigned v = swpn[(dr * HH + hh + t) * SWSTR + c];
            a = pkmin(a, v + (unsigned)((t - 4) * (t - 4)) * 0x00010001u);
        }
        whpn[(dr * HT + hh) * WT + c] = a;
    }
    __syncthreads();

    // ---- stage C: D pass + loss on interior 8d x 8h x 32w ----
    float num = 0.f, den = 0.f;
    #pragma unroll
    for (int k = 0; k < 8; ++k) {
        const int idx = tid + 256 * k;         // (di 0..7, hh 0..7, c 0..31)
        const int c   = idx & 31;
        const int hh  = (idx >> 5) & 7;
        const int di  = idx >> 8;
        unsigned a = 0x00190019u;
        #pragma unroll
        for (int t = 0; t < 9; ++t) {
            const unsigned v = whpn[((di + t) * HT + hh) * WT + c];
            a = pkmin(a, v + (unsigned)((t - 4) * (t - 4)) * 0x00010001u);
        }
        const size_t g = ((size_t)(bi * DDIM + d0 + di) * HDIM + h0 + hh) * WDIM + w0 + c;
        const float pr = pred[g];
        const float tg = target[g];
        const float dp = sqrtf((float)(a & 0xFFFFu));        // dist to bg
        const float dn = sqrtf((float)(a >> 16));            // dist to fg
        const float aa = fabsf(dn - dp);
        float w;
        if (aa <= 3.0f)      w = 1.0f;
        else if (aa >= 5.0f) w = 0.0f;
        else                 w = 1.0f - (aa - 3.0f) * 0.5f;
        const float lp  = fmaxf(logf(pr), -100.0f);
        const float l1  = fmaxf(logf(1.0f - pr), -100.0f);
        const float bce = -(tg * lp + (1.0f - tg) * l1);
        num += bce * w;
        den += w;
    }

    // ---- wave reduce -> cross-wave LDS -> one atomic pair per block ----
    for (int off = 32; off > 0; off >>= 1) {
        num += __shfl_down(num, off);
        den += __shfl_down(den, off);
    }
    if ((tid & 63) == 0) {
        rsum[tid >> 6]       = num;
        rsum[4 + (tid >> 6)] = den;
    }
    __syncthreads();
    if (tid == 0) {
        float ns = rsum[0] + rsum[1] + rsum[2] + rsum[3];
        float ds = rsum[4] + rsum[5] + rsum[6] + rsum[7];
        atomicAdd(&acc[bi], ns);
        atomicAdd(&acc[2 + bi], ds);
        __threadfence();
        int done = atomicAdd((int*)acc + 4, 1);
        if (done == NBLK - 1) {                // last block: finalize
            __threadfence();
            float n0  = atomicAdd(&acc[0], 0.0f);
            float n1  = atomicAdd(&acc[1], 0.0f);
            float d0_ = atomicAdd(&acc[2], 0.0f);
            float d1_ = atomicAdd(&acc[3], 0.0f);
            out[0] = 0.5f * (n0 / (d0_ + 1e-5f) + n1 / (d1_ + 1e-5f));
        }
    }
}

extern "C" void kernel_launch(void* const* d_in, const int* in_sizes, int n_in,
                              void* d_out, int out_size, void* d_ws, size_t ws_size,
                              hipStream_t stream) {
    const float* pred   = (const float*)d_in[0];
    const float* target = (const float*)d_in[1];
    float* acc = (float*)d_ws;          // 4 floats num/den + 1 int counter
    float* out = (float*)d_out;

    init_acc<<<1, 64, 0, stream>>>(acc);
    boundary_fused<<<NBLK, 256, 0, stream>>>(pred, target, acc, out);
}